// Round 1
// baseline (328.675 us; speedup 1.0000x reference)
//
#include <hip/hip_runtime.h>

// Correlation1D on MI355X (gfx950).
// out[b,d,h,w] = (1/256) * sum_c in1[b,c,h,w] * in2[b,c,h,w+d-40]
// B=8 C=256 H=96 W=192 D=81 PAD=40.
//
// Formulation: per (b,h) row, banded GEMM C[w,j] = sum_c A[c,w]*B[c,j],
// j = w+d in padded coords [0,272). bf16 MFMA 16x16x32, fp32 accumulate.
// One block per (b,h): grid 768 = 3 blocks/CU exactly. HBM-bound design:
// reads are exactly minimal (302 MB), writes coalesced via LDS transpose.

typedef __attribute__((ext_vector_type(8))) short short8;     // 8 bf16 = 4 VGPR
typedef __attribute__((ext_vector_type(4))) float float4v;
typedef __attribute__((ext_vector_type(4))) int int4v;

__device__ __forceinline__ unsigned short f2bf(float f) {
  // round-to-nearest-even fp32 -> bf16
  unsigned int u = __float_as_uint(f);
  return (unsigned short)((u + 0x7FFFu + ((u >> 16) & 1u)) >> 16);
}

__global__ __launch_bounds__(256, 3) void corr1d_kernel(
    const float* __restrict__ in1, const float* __restrict__ in2,
    float* __restrict__ out) {
  constexpr int W = 192, H = 96, C = 256, D = 81, PAD = 40;
  constexpr int HW = H * W;          // 18432, c-stride in elements
  constexpr int KC = 32;             // k-chunk per staging pass (1 MFMA K each)
  constexpr int STR = 40;            // LDS k-stride (32 + 8 pad -> conflict-free b128)

  // LDS union: staging (A 192*40 + B 272*40 ushorts = 37120 B) vs epilogue
  // (81*97 floats = 31428 B). Max = 37120 B -> 3 blocks/CU fits easily.
  __shared__ __align__(16) unsigned short smem[18560];
  unsigned short* A_l = smem;                 // [w][k]  192*40
  unsigned short* B_l = smem + 192 * STR;     // [j][k]  272*40
  float* E = (float*)smem;                    // [d][97] epilogue transpose

  const int bh = blockIdx.x;
  const int b = bh / H;
  const int h = bh % H;
  const int tid = threadIdx.x;
  const int lane = tid & 63;
  const int wv = tid >> 6;                    // wave 0..3
  const int l15 = lane & 15;
  const int lq = lane >> 4;                   // quad 0..3

  // ---- zero the B halo columns once (j<40 and j>=232, k<32); never re-staged
  for (int idx = tid; idx < 80 * 32; idx += 256) {
    int col = idx >> 5;                       // 0..79
    int k = idx & 31;
    int j = (col < PAD) ? col : (W + col);    // 0..39 or 232..271
    B_l[j * STR + k] = 0;
  }

  // ---- accumulators: wave wv owns w-tiles 3wv..3wv+2, each x 6 j-tiles
  float4v acc[3][6];
#pragma unroll
  for (int i = 0; i < 3; ++i)
#pragma unroll
    for (int jj = 0; jj < 6; ++jj)
      acc[i][jj] = (float4v){0.f, 0.f, 0.f, 0.f};

  const int base1 = (b * C * H + h) * W;      // offset of (b, c=0, h, w=0)

  // ---- K loop over channels
  for (int c0 = 0; c0 < C; c0 += KC) {
    __syncthreads();                          // LDS free from previous compute

    // stage: 384 tasks, each = 4 cols x 8 c -> 8 global dwordx4, 4 ds_write_b128
    for (int t = tid; t < 384; t += 256) {
      const int isB = t >= 192;
      const int u = isB ? t - 192 : t;
      const float* src = isB ? in2 : in1;
      unsigned short* dst = isB ? (B_l + PAD * STR) : A_l;   // B: j = w' + 40
      const int w0 = 4 * (u % 48);            // consecutive tasks -> coalesced
      const int co = 8 * (u / 48);
      const int g = base1 + (c0 + co) * HW + w0;
      float4v v[8];
#pragma unroll
      for (int i = 0; i < 8; ++i)
        v[i] = *(const float4v*)(src + g + i * HW);
#pragma unroll
      for (int x = 0; x < 4; ++x) {
        unsigned short o[8];
#pragma unroll
        for (int i = 0; i < 8; ++i) o[i] = f2bf(v[i][x]);
        *(int4v*)(dst + (w0 + x) * STR + co) = *(const int4v*)o;
      }
    }
    __syncthreads();

    // compute: A-frag A[m=lane&15][k=quad*8+j], B-frag B[k=quad*8+j][n=lane&15]
    short8 af[3];
#pragma unroll
    for (int i = 0; i < 3; ++i) {
      const int wt = 3 * wv + i;
      af[i] = *(const short8*)(A_l + (16 * wt + l15) * STR + 8 * lq);
    }
#pragma unroll
    for (int jt = 0; jt < 8; ++jt) {          // absolute j-tile = 3wv + jt
      const int ja = 3 * wv + jt;
      short8 bf = *(const short8*)(B_l + (16 * ja + l15) * STR + 8 * lq);
#pragma unroll
      for (int i = 0; i < 3; ++i) {
        const int jj = jt - i;                // compile-time after unroll
        if (jj >= 0 && jj < 6)
          acc[i][jj] = __builtin_amdgcn_mfma_f32_16x16x32_bf16(
              af[i], bf, acc[i][jj], 0, 0, 0);
      }
    }
  }

  // ---- epilogue: D layout row=quad*4+reg (=w), col=lane&15 (=j).
  // Two phases by w-half; transpose through LDS for coalesced w-major stores.
  const float scale = 1.0f / 256.0f;
#pragma unroll
  for (int p = 0; p < 2; ++p) {
    __syncthreads();                          // E region free
    if ((wv >> 1) == p) {                     // waves owning w in [96p, 96p+96)
#pragma unroll
      for (int i = 0; i < 3; ++i) {
        const int wt = 3 * wv + i;
#pragma unroll
        for (int jj = 0; jj < 6; ++jj) {
          const int j = 16 * (wt + jj) + l15;
#pragma unroll
          for (int r = 0; r < 4; ++r) {
            const int w = 16 * wt + 4 * lq + r;
            const int d = j - w;
            if (d >= 0 && d < D)
              E[d * 97 + (w - 96 * p)] = acc[i][jj][r] * scale;
          }
        }
      }
    }
    __syncthreads();
    float* outp = out + (b * D * H + h) * W + 96 * p;
    for (int idx = tid; idx < D * 96; idx += 256) {
      const int d = idx / 96;
      const int w = idx - d * 96;
      outp[d * HW + w] = E[d * 97 + w];
    }
  }
}

extern "C" void kernel_launch(void* const* d_in, const int* in_sizes, int n_in,
                              void* d_out, int out_size, void* d_ws, size_t ws_size,
                              hipStream_t stream) {
  const float* in1 = (const float*)d_in[0];
  const float* in2 = (const float*)d_in[1];
  float* out = (float*)d_out;
  (void)in_sizes; (void)n_in; (void)out_size; (void)d_ws; (void)ws_size;
  corr1d_kernel<<<dim3(768), dim3(256), 0, stream>>>(in1, in2, out);
}